// Round 9
// baseline (55.442 us; speedup 1.0000x reference)
//
#include <hip/hip_runtime.h>
#include <math.h>

#define HW_ 1024

typedef __attribute__((ext_vector_type(4))) float   f32x4;
typedef __attribute__((ext_vector_type(8))) short   s16x8;

__device__ __forceinline__ unsigned bf16rne(float x) {
  unsigned u = __builtin_bit_cast(unsigned, x);
  u += 0x7FFF + ((u >> 16) & 1);
  return u >> 16;
}

// ---------------- K1: fused 1x1 convs (conv_out + q/k/v staging, bf16) ----------------
// grid 1024 = b(4) x ocq(64) x pt(4); 256 thr = 4 oc x 64 p-quads
__global__ __launch_bounds__(256) void k_convs(
    const float* __restrict__ x, const float* __restrict__ w_conv, const float* __restrict__ b_conv,
    const float* __restrict__ w_qkv, const float* __restrict__ b_qkv,
    float* __restrict__ out,
    ushort* __restrict__ qbf, ushort* __restrict__ kbf, ushort* __restrict__ vtg)
{
  int bid = blockIdx.x;
  int pt  = bid & 3;
  int ocq = (bid >> 2) & 63;
  int b   = bid >> 8;
  int tid = threadIdx.x;
  int oc  = ocq * 4 + (tid >> 6);          // 0..255 (wave-uniform)
  int p   = pt * 256 + (tid & 63) * 4;

  const float* wrow;
  float bias;
  if (oc < 64) { wrow = w_conv + oc * 64; bias = b_conv[oc]; }
  else         { wrow = w_qkv + (oc - 64) * 64; bias = b_qkv[oc - 64]; }

  float4 a0 = make_float4(bias, bias, bias, bias);
  float4 a1 = make_float4(0.f, 0.f, 0.f, 0.f);
  const float* xb = x + (size_t)b * 64 * HW_ + p;
  #pragma unroll 16
  for (int ci = 0; ci < 32; ++ci) {
    float w0 = wrow[ci], w1 = wrow[ci + 32];
    float4 x0 = *(const float4*)(xb + (size_t)ci * HW_);
    float4 x1 = *(const float4*)(xb + (size_t)(ci + 32) * HW_);
    a0.x = fmaf(w0, x0.x, a0.x); a1.x = fmaf(w1, x1.x, a1.x);
    a0.y = fmaf(w0, x0.y, a0.y); a1.y = fmaf(w1, x1.y, a1.y);
    a0.z = fmaf(w0, x0.z, a0.z); a1.z = fmaf(w1, x1.z, a1.z);
    a0.w = fmaf(w0, x0.w, a0.w); a1.w = fmaf(w1, x1.w, a1.w);
  }
  float4 acc = make_float4(a0.x + a1.x, a0.y + a1.y, a0.z + a1.z, a0.w + a1.w);

  float av[4] = {acc.x, acc.y, acc.z, acc.w};
  if (oc < 64) {
    *(float4*)(out + ((size_t)b * 128 + oc) * HW_ + p) = acc;
  } else if (oc < 128) {
    const float SC = 0.35355339059327373f * 1.4426950408889634f;  // dkh^-0.5 * log2e
    int qc = oc - 64, n = qc >> 3, d = qc & 7, bn = b * 8 + n;
    #pragma unroll
    for (int i = 0; i < 4; ++i)
      qbf[((size_t)bn * HW_ + p + i) * 8 + d] = (ushort)bf16rne(av[i] * SC);
  } else if (oc < 192) {
    int kc = oc - 128, n = kc >> 3, d = kc & 7, bn = b * 8 + n;
    #pragma unroll
    for (int i = 0; i < 4; ++i)
      kbf[((size_t)bn * HW_ + p + i) * 8 + d] = (ushort)bf16rne(av[i]);
  } else {
    int vc = oc - 192, n = vc >> 3, d = vc & 7, bn = b * 8 + n;
    #pragma unroll
    for (int i = 0; i < 4; ++i)
      vtg[((size_t)bn * 8 + d) * HW_ + p + i] = (ushort)bf16rne(av[i]);
  }
}

// ---------------- K2: MFMA flash attention, key-split 2-way (R6-verbatim) ----------------
// grid 512 = bn(32) x qt(16); 512 thr = 8 waves: qsub(4) x key-half(2)
// wave: 16 q-cols x 512 keys. S^T = mfma(K, Q^T, C=rel); P via per-wave
// swizzled LDS; O^T = mfma(V^T(+ones row), P^T, O); l rides in O row d=8.
__global__ __launch_bounds__(512, 4) void k_attn(
    const ushort* __restrict__ qbf, const ushort* __restrict__ kbf, const ushort* __restrict__ vtg,
    const float* __restrict__ rel_h, const float* __restrict__ rel_w,
    float* __restrict__ aws)
{
  __shared__ float rhd[64 * 33];
  __shared__ float rwd[64 * 33];
  __shared__ ushort P_lds[8][16][128];   // per-wave [q][key], 256B rows, XOR-swizzled
  __shared__ float mbuf[4][16], lbuf[4][16];
  __shared__ float obuf[4][16][8];

  int bid = blockIdx.x;
  int qt = bid & 15;
  int bn = bid >> 4;
  int b = bn >> 3, n = bn & 7;
  int tid = threadIdx.x;
  int lane = tid & 63;
  int w = tid >> 6;
  int qsub = w & 3, half = w >> 2;

  // ---- build rel tables: rhd[qr][hp] = q.rel_h[hp-h+31], rwd[qr][wp] = q.rel_w[wp-w+31]
  {
    int qr = tid >> 3, qu = tid & 7;
    const ushort* qp = qbf + ((size_t)bn * HW_ + qt * 64 + qr) * 8;
    float qf[8];
    #pragma unroll
    for (int d = 0; d < 8; ++d) qf[d] = __builtin_bit_cast(float, (unsigned)qp[d] << 16);
    int h = (qt * 64 + qr) >> 5, ww = qr & 31;
    #pragma unroll
    for (int s = 0; s < 4; ++s) {
      int idx = qu * 4 + s;
      const float* rp = rel_h + (idx - h + 31) * 8;
      float a = 0.f;
      #pragma unroll
      for (int d = 0; d < 8; ++d) a = fmaf(qf[d], rp[d], a);
      rhd[qr * 33 + idx] = a;
      const float* rq = rel_w + (idx - ww + 31) * 8;
      float c = 0.f;
      #pragma unroll
      for (int d = 0; d < 8; ++d) c = fmaf(qf[d], rq[d], c);
      rwd[qr * 33 + idx] = c;
    }
  }
  __syncthreads();

  int q = lane & 15, g = lane >> 4;
  int qr = qsub * 16 + q;

  s16x8 qfrag = {0,0,0,0,0,0,0,0};
  if (lane < 16)
    qfrag = *(const s16x8*)(qbf + ((size_t)bn * HW_ + qt * 64 + qsub * 16 + lane) * 8);

  float rw2[2][4];
  #pragma unroll
  for (int r = 0; r < 4; ++r) {
    rw2[0][r] = rwd[qr * 33 + g * 4 + r];
    rw2[1][r] = rwd[qr * 33 + 16 + g * 4 + r];
  }

  const ushort* kbase = kbf + (size_t)bn * HW_ * 8;
  const ushort* vbase = vtg + (size_t)bn * 8 * HW_;

  s16x8 vone;
  #pragma unroll
  for (int e = 0; e < 8; ++e) vone[e] = (short)0x3F80;   // bf16 1.0
  s16x8 vzero = {0,0,0,0,0,0,0,0};

  float m = -1e30f;
  f32x4 O = {0.f, 0.f, 0.f, 0.f};

  char* prow = (char*)&P_lds[w][0][0] + q * 256;
  int sw = (q & 7) << 4;

  #pragma unroll
  for (int bki = 0; bki < 4; ++bki) {
    int bk = half * 4 + bki;
    float rh4[4];
    #pragma unroll
    for (int j = 0; j < 4; ++j) rh4[j] = rhd[qr * 33 + bk * 4 + j];

    // ---- QK^T (S^T), rel logits as C-init
    f32x4 s[8];
    #pragma unroll
    for (int t = 0; t < 8; ++t) {
      f32x4 c;
      #pragma unroll
      for (int r = 0; r < 4; ++r) c[r] = rh4[t >> 1] + rw2[t & 1][r];
      s16x8 kf = {0,0,0,0,0,0,0,0};
      if (lane < 16)
        kf = *(const s16x8*)(kbase + (size_t)(bk * 128 + t * 16 + lane) * 8);
      s[t] = __builtin_amdgcn_mfma_f32_16x16x32_bf16(kf, qfrag, c, 0, 0, 0);
    }

    // ---- online softmax max (base-2 domain)
    float t8[8];
    #pragma unroll
    for (int t = 0; t < 8; ++t)
      t8[t] = fmaxf(fmaxf(s[t][0], s[t][1]), fmaxf(s[t][2], s[t][3]));
    float mx = fmaxf(fmaxf(fmaxf(t8[0], t8[1]), fmaxf(t8[2], t8[3])),
                     fmaxf(fmaxf(t8[4], t8[5]), fmaxf(t8[6], t8[7])));
    mx = fmaxf(mx, __shfl_xor(mx, 16));
    mx = fmaxf(mx, __shfl_xor(mx, 32));
    float mn = fmaxf(m, mx);
    float corr = __builtin_amdgcn_exp2f(m - mn);
    m = mn;

    #pragma unroll
    for (int t = 0; t < 8; ++t)
      #pragma unroll
      for (int r = 0; r < 4; ++r)
        s[t][r] = __builtin_amdgcn_exp2f(s[t][r] - mn);

    #pragma unroll
    for (int r = 0; r < 4; ++r) O[r] *= corr;

    // ---- pack P (RNE via cvt_pk) into swizzled per-wave LDS
    #pragma unroll
    for (int t = 0; t < 8; ++t) {
      unsigned w0, w1;
      asm("v_cvt_pk_bf16_f32 %0, %1, %2" : "=v"(w0) : "v"(s[t][0]), "v"(s[t][1]));
      asm("v_cvt_pk_bf16_f32 %0, %1, %2" : "=v"(w1) : "v"(s[t][2]), "v"(s[t][3]));
      *(uint2*)(prow + (((t * 32 + g * 8) ^ sw))) = make_uint2(w0, w1);
    }
    asm volatile("s_waitcnt lgkmcnt(0)" ::: "memory");

    // ---- PV: O^T += [V^T; ones] . P^T
    #pragma unroll
    for (int km = 0; km < 4; ++km) {
      s16x8 pfrag = *(const s16x8*)(prow + ((km * 64 + g * 16) ^ sw));
      s16x8 vf;
      if (q < 8)      vf = *(const s16x8*)(vbase + (size_t)q * HW_ + bk * 128 + km * 32 + g * 8);
      else if (q == 8) vf = vone;
      else             vf = vzero;
      O = __builtin_amdgcn_mfma_f32_16x16x32_bf16(vf, pfrag, O, 0, 0, 0);
    }
  }

  // l = row d=8 of O^T (lane 32+q, reg 0)
  float l = __shfl(O[0], 32 + q);

  // ---- merge the two key-halves via LDS
  if (half == 1) {
    if (g < 2) {
      #pragma unroll
      for (int r = 0; r < 4; ++r) obuf[qsub][q][g * 4 + r] = O[r];
    }
    if (lane < 16) { mbuf[qsub][lane] = m; lbuf[qsub][lane] = l; }
  }
  __syncthreads();
  if (half == 0 && g < 2) {
    float m2 = mbuf[qsub][q], l2 = lbuf[qsub][q];
    float mn = fmaxf(m, m2);
    float c1 = __builtin_amdgcn_exp2f(m - mn);
    float c2 = __builtin_amdgcn_exp2f(m2 - mn);
    float inv = 1.f / (l * c1 + l2 * c2);
    int qrow = qt * 64 + qsub * 16 + q;
    float* ap = aws + ((size_t)b * 64 + n * 8) * HW_;
    #pragma unroll
    for (int r = 0; r < 4; ++r)
      ap[(size_t)(g * 4 + r) * HW_ + qrow] = (O[r] * c1 + obuf[qsub][q][g * 4 + r] * c2) * inv;
  }
}

// ---------------- K3: 1x1 conv on attention map, ci-split-4 ----------------
// grid 1024 = b(4) x ocg(16) x pt(16); 256 thr = 4 waves(oc) x [16 pq x 4 ci4]
__global__ __launch_bounds__(256) void k_attnconv(
    const float* __restrict__ aws, const float* __restrict__ w_attn, const float* __restrict__ b_attn,
    float* __restrict__ out)
{
  int bid = blockIdx.x;
  int pt  = bid & 15;
  int ocg = (bid >> 4) & 15;
  int b   = bid >> 8;
  int tid = threadIdx.x;
  int lane = tid & 63;
  int oc  = ocg * 4 + (tid >> 6);
  int pq  = lane >> 2, ci4 = lane & 3;
  int p   = pt * 64 + pq * 4;
  int ci0 = ci4 * 16;

  const float* wrow = w_attn + oc * 64 + ci0;
  const float* ab = aws + (size_t)b * 64 * HW_ + (size_t)ci0 * HW_ + p;
  float4 acc = make_float4(0.f, 0.f, 0.f, 0.f);
  #pragma unroll
  for (int ci = 0; ci < 16; ++ci) {
    float wv = wrow[ci];
    float4 a4 = *(const float4*)(ab + (size_t)ci * HW_);
    acc.x = fmaf(wv, a4.x, acc.x);
    acc.y = fmaf(wv, a4.y, acc.y);
    acc.z = fmaf(wv, a4.z, acc.z);
    acc.w = fmaf(wv, a4.w, acc.w);
  }
  #pragma unroll
  for (int off = 1; off <= 2; off <<= 1) {
    acc.x += __shfl_xor(acc.x, off);
    acc.y += __shfl_xor(acc.y, off);
    acc.z += __shfl_xor(acc.z, off);
    acc.w += __shfl_xor(acc.w, off);
  }
  if (ci4 == 0) {
    float bias = b_attn[oc];
    float4 r = make_float4(acc.x + bias, acc.y + bias, acc.z + bias, acc.w + bias);
    *(float4*)(out + ((size_t)b * 128 + 64 + oc) * HW_ + p) = r;
  }
}

extern "C" void kernel_launch(void* const* d_in, const int* in_sizes, int n_in,
                              void* d_out, int out_size, void* d_ws, size_t ws_size,
                              hipStream_t stream) {
  const float* x        = (const float*)d_in[0];
  const float* w_conv   = (const float*)d_in[1];
  const float* b_conv   = (const float*)d_in[2];
  const float* w_qkv    = (const float*)d_in[3];
  const float* b_qkv    = (const float*)d_in[4];
  const float* w_attn   = (const float*)d_in[5];
  const float* b_attn   = (const float*)d_in[6];
  const float* rel_h    = (const float*)d_in[7];
  const float* rel_w    = (const float*)d_in[8];
  float* out = (float*)d_out;

  float*  ws  = (float*)d_ws;
  float*  aws = ws;                               // [4][64][1024] f32 (1MB)
  ushort* qbf = (ushort*)(ws + 262144);           // [32][1024][8] bf16 (512KB)
  ushort* kbf = qbf + 262144;                     // [32][1024][8] bf16 (512KB)
  ushort* vtg = kbf + 262144;                     // [32][8][1024] bf16 (512KB)

  k_convs<<<1024, 256, 0, stream>>>(x, w_conv, b_conv, w_qkv, b_qkv, out, qbf, kbf, vtg);
  k_attn<<<512, 512, 0, stream>>>(qbf, kbf, vtg, rel_h, rel_w, aws);
  k_attnconv<<<1024, 256, 0, stream>>>(aws, w_attn, b_attn, out);
}

// Round 11
// 45.360 us; speedup vs baseline: 1.2223x; 1.2223x over previous
//
#include <hip/hip_runtime.h>
#include <math.h>

#define HW_ 1024

typedef __attribute__((ext_vector_type(4))) float   f32x4;
typedef __attribute__((ext_vector_type(8))) short   s16x8;

__device__ __forceinline__ unsigned bf16rne(float x) {
  unsigned u = __builtin_bit_cast(unsigned, x);
  u += 0x7FFF + ((u >> 16) & 1);
  return u >> 16;
}

__device__ __forceinline__ void store_oc(int oc, const float av[4],
    float* __restrict__ out, ushort* __restrict__ qbf, ushort* __restrict__ kbf,
    ushort* __restrict__ vtg, int b, int p)
{
  if (oc < 64) {
    float4 acc = make_float4(av[0], av[1], av[2], av[3]);
    *(float4*)(out + ((size_t)b * 128 + oc) * HW_ + p) = acc;
  } else if (oc < 128) {
    const float SC = 0.35355339059327373f * 1.4426950408889634f;  // dkh^-0.5 * log2e
    int qc = oc - 64, n = qc >> 3, d = qc & 7, bn = b * 8 + n;
    #pragma unroll
    for (int i = 0; i < 4; ++i)
      qbf[((size_t)bn * HW_ + p + i) * 8 + d] = (ushort)bf16rne(av[i] * SC);
  } else if (oc < 192) {
    int kc = oc - 128, n = kc >> 3, d = kc & 7, bn = b * 8 + n;
    #pragma unroll
    for (int i = 0; i < 4; ++i)
      kbf[((size_t)bn * HW_ + p + i) * 8 + d] = (ushort)bf16rne(av[i]);
  } else {
    int vc = oc - 192, n = vc >> 3, d = vc & 7, bn = b * 8 + n;
    #pragma unroll
    for (int i = 0; i < 4; ++i)
      vtg[((size_t)bn * 8 + d) * HW_ + p + i] = (ushort)bf16rne(av[i]);
  }
}

// ---------------- K1: fused 1x1 convs, 2 oc/thread ----------------
// grid 512 = b(4) x ocp(32) x pt(4); 256 thr; thread: oc0=ocp*8+(tid>>6)*2, oc0+1
__global__ __launch_bounds__(256) void k_convs(
    const float* __restrict__ x, const float* __restrict__ w_conv, const float* __restrict__ b_conv,
    const float* __restrict__ w_qkv, const float* __restrict__ b_qkv,
    float* __restrict__ out,
    ushort* __restrict__ qbf, ushort* __restrict__ kbf, ushort* __restrict__ vtg)
{
  int bid = blockIdx.x;
  int pt  = bid & 3;
  int ocp = (bid >> 2) & 31;
  int b   = bid >> 7;
  int tid = threadIdx.x;
  int oc0 = ocp * 8 + (tid >> 6) * 2;      // even; pair stays within region
  int oc1 = oc0 + 1;
  int p   = pt * 256 + (tid & 63) * 4;

  const float* wrow0; const float* wrow1;
  float bias0, bias1;
  if (oc0 < 64) { wrow0 = w_conv + oc0 * 64; bias0 = b_conv[oc0];
                  wrow1 = w_conv + oc1 * 64; bias1 = b_conv[oc1]; }
  else          { wrow0 = w_qkv + (oc0 - 64) * 64; bias0 = b_qkv[oc0 - 64];
                  wrow1 = w_qkv + (oc1 - 64) * 64; bias1 = b_qkv[oc1 - 64]; }

  float4 a00 = make_float4(bias0, bias0, bias0, bias0);
  float4 a01 = make_float4(0.f, 0.f, 0.f, 0.f);
  float4 a10 = make_float4(bias1, bias1, bias1, bias1);
  float4 a11 = make_float4(0.f, 0.f, 0.f, 0.f);
  const float* xb = x + (size_t)b * 64 * HW_ + p;
  #pragma unroll 16
  for (int ci = 0; ci < 32; ++ci) {
    float4 x0 = *(const float4*)(xb + (size_t)ci * HW_);
    float4 x1 = *(const float4*)(xb + (size_t)(ci + 32) * HW_);
    float w00 = wrow0[ci], w01 = wrow0[ci + 32];
    float w10 = wrow1[ci], w11 = wrow1[ci + 32];
    a00.x = fmaf(w00, x0.x, a00.x); a01.x = fmaf(w01, x1.x, a01.x);
    a00.y = fmaf(w00, x0.y, a00.y); a01.y = fmaf(w01, x1.y, a01.y);
    a00.z = fmaf(w00, x0.z, a00.z); a01.z = fmaf(w01, x1.z, a01.z);
    a00.w = fmaf(w00, x0.w, a00.w); a01.w = fmaf(w01, x1.w, a01.w);
    a10.x = fmaf(w10, x0.x, a10.x); a11.x = fmaf(w11, x1.x, a11.x);
    a10.y = fmaf(w10, x0.y, a10.y); a11.y = fmaf(w11, x1.y, a11.y);
    a10.z = fmaf(w10, x0.z, a10.z); a11.z = fmaf(w11, x1.z, a11.z);
    a10.w = fmaf(w10, x0.w, a10.w); a11.w = fmaf(w11, x1.w, a11.w);
  }
  float av0[4] = {a00.x + a01.x, a00.y + a01.y, a00.z + a01.z, a00.w + a01.w};
  float av1[4] = {a10.x + a11.x, a10.y + a11.y, a10.z + a11.z, a10.w + a11.w};
  store_oc(oc0, av0, out, qbf, kbf, vtg, b, p);
  store_oc(oc1, av1, out, qbf, kbf, vtg, b, p);
}

// ---------------- K2: MFMA flash attention, key-split 2-way (R9 + V-hoist + setprio) ----------------
// grid 512 = bn(32) x qt(16); 512 thr = 8 waves: qsub(4) x key-half(2)
// wave: 16 q-cols x 512 keys. S^T = mfma(K, Q^T, C=rel); P via per-wave
// swizzled LDS; O^T = mfma(V^T(+ones row), P^T, O); l rides in O row d=8.
__global__ __launch_bounds__(512, 4) void k_attn(
    const ushort* __restrict__ qbf, const ushort* __restrict__ kbf, const ushort* __restrict__ vtg,
    const float* __restrict__ rel_h, const float* __restrict__ rel_w,
    float* __restrict__ aws)
{
  __shared__ float rhd[64 * 33];
  __shared__ float rwd[64 * 33];
  __shared__ ushort P_lds[8][16][128];   // per-wave [q][key], 256B rows, XOR-swizzled
  __shared__ float mbuf[4][16], lbuf[4][16];
  __shared__ float obuf[4][16][8];

  int bid = blockIdx.x;
  int qt = bid & 15;
  int bn = bid >> 4;
  int b = bn >> 3, n = bn & 7;
  int tid = threadIdx.x;
  int lane = tid & 63;
  int w = tid >> 6;
  int qsub = w & 3, half = w >> 2;

  // ---- build rel tables: rhd[qr][hp] = q.rel_h[hp-h+31], rwd[qr][wp] = q.rel_w[wp-w+31]
  {
    int qr = tid >> 3, qu = tid & 7;
    const ushort* qp = qbf + ((size_t)bn * HW_ + qt * 64 + qr) * 8;
    float qf[8];
    #pragma unroll
    for (int d = 0; d < 8; ++d) qf[d] = __builtin_bit_cast(float, (unsigned)qp[d] << 16);
    int h = (qt * 64 + qr) >> 5, ww = qr & 31;
    #pragma unroll
    for (int s = 0; s < 4; ++s) {
      int idx = qu * 4 + s;
      const float* rp = rel_h + (idx - h + 31) * 8;
      float a = 0.f;
      #pragma unroll
      for (int d = 0; d < 8; ++d) a = fmaf(qf[d], rp[d], a);
      rhd[qr * 33 + idx] = a;
      const float* rq = rel_w + (idx - ww + 31) * 8;
      float c = 0.f;
      #pragma unroll
      for (int d = 0; d < 8; ++d) c = fmaf(qf[d], rq[d], c);
      rwd[qr * 33 + idx] = c;
    }
  }
  __syncthreads();

  int q = lane & 15, g = lane >> 4;
  int qr = qsub * 16 + q;

  s16x8 qfrag = {0,0,0,0,0,0,0,0};
  if (lane < 16)
    qfrag = *(const s16x8*)(qbf + ((size_t)bn * HW_ + qt * 64 + qsub * 16 + lane) * 8);

  float rw2[2][4];
  #pragma unroll
  for (int r = 0; r < 4; ++r) {
    rw2[0][r] = rwd[qr * 33 + g * 4 + r];
    rw2[1][r] = rwd[qr * 33 + 16 + g * 4 + r];
  }

  const ushort* kbase = kbf + (size_t)bn * HW_ * 8;
  const ushort* vbase = vtg + (size_t)bn * 8 * HW_;

  s16x8 vone;
  #pragma unroll
  for (int e = 0; e < 8; ++e) vone[e] = (short)0x3F80;   // bf16 1.0
  s16x8 vzero = {0,0,0,0,0,0,0,0};

  float m = -1e30f;
  f32x4 O = {0.f, 0.f, 0.f, 0.f};

  char* prow = (char*)&P_lds[w][0][0] + q * 256;
  int sw = (q & 7) << 4;

  #pragma unroll
  for (int bki = 0; bki < 4; ++bki) {
    int bk = half * 4 + bki;
    float rh4[4];
    #pragma unroll
    for (int j = 0; j < 4; ++j) rh4[j] = rhd[qr * 33 + bk * 4 + j];

    // ---- QK^T (S^T), rel logits as C-init
    f32x4 s[8];
    __builtin_amdgcn_s_setprio(1);
    #pragma unroll
    for (int t = 0; t < 8; ++t) {
      f32x4 c;
      #pragma unroll
      for (int r = 0; r < 4; ++r) c[r] = rh4[t >> 1] + rw2[t & 1][r];
      s16x8 kf = {0,0,0,0,0,0,0,0};
      if (lane < 16)
        kf = *(const s16x8*)(kbase + (size_t)(bk * 128 + t * 16 + lane) * 8);
      s[t] = __builtin_amdgcn_mfma_f32_16x16x32_bf16(kf, qfrag, c, 0, 0, 0);
    }
    __builtin_amdgcn_s_setprio(0);

    // ---- hoisted V fragments for this bk (issue loads before the pack/fence)
    s16x8 vfr[4];
    #pragma unroll
    for (int km = 0; km < 4; ++km) {
      if (q < 8)      vfr[km] = *(const s16x8*)(vbase + (size_t)q * HW_ + bk * 128 + km * 32 + g * 8);
      else if (q == 8) vfr[km] = vone;
      else             vfr[km] = vzero;
    }

    // ---- online softmax max (base-2 domain)
    float t8[8];
    #pragma unroll
    for (int t = 0; t < 8; ++t)
      t8[t] = fmaxf(fmaxf(s[t][0], s[t][1]), fmaxf(s[t][2], s[t][3]));
    float mx = fmaxf(fmaxf(fmaxf(t8[0], t8[1]), fmaxf(t8[2], t8[3])),
                     fmaxf(fmaxf(t8[4], t8[5]), fmaxf(t8[6], t8[7])));
    mx = fmaxf(mx, __shfl_xor(mx, 16));
    mx = fmaxf(mx, __shfl_xor(mx, 32));
    float mn = fmaxf(m, mx);
    float corr = __builtin_amdgcn_exp2f(m - mn);
    m = mn;

    #pragma unroll
    for (int t = 0; t < 8; ++t)
      #pragma unroll
      for (int r = 0; r < 4; ++r)
        s[t][r] = __builtin_amdgcn_exp2f(s[t][r] - mn);

    #pragma unroll
    for (int r = 0; r < 4; ++r) O[r] *= corr;

    // ---- pack P (RNE via cvt_pk) into swizzled per-wave LDS
    #pragma unroll
    for (int t = 0; t < 8; ++t) {
      unsigned w0, w1;
      asm("v_cvt_pk_bf16_f32 %0, %1, %2" : "=v"(w0) : "v"(s[t][0]), "v"(s[t][1]));
      asm("v_cvt_pk_bf16_f32 %0, %1, %2" : "=v"(w1) : "v"(s[t][2]), "v"(s[t][3]));
      *(uint2*)(prow + (((t * 32 + g * 8) ^ sw))) = make_uint2(w0, w1);
    }
    asm volatile("s_waitcnt lgkmcnt(0)" ::: "memory");

    // ---- PV: O^T += [V^T; ones] . P^T
    __builtin_amdgcn_s_setprio(1);
    #pragma unroll
    for (int km = 0; km < 4; ++km) {
      s16x8 pfrag = *(const s16x8*)(prow + ((km * 64 + g * 16) ^ sw));
      O = __builtin_amdgcn_mfma_f32_16x16x32_bf16(vfr[km], pfrag, O, 0, 0, 0);
    }
    __builtin_amdgcn_s_setprio(0);
  }

  // l = row d=8 of O^T (lane 32+q, reg 0)
  float l = __shfl(O[0], 32 + q);

  // ---- merge the two key-halves via LDS
  if (half == 1) {
    if (g < 2) {
      #pragma unroll
      for (int r = 0; r < 4; ++r) obuf[qsub][q][g * 4 + r] = O[r];
    }
    if (lane < 16) { mbuf[qsub][lane] = m; lbuf[qsub][lane] = l; }
  }
  __syncthreads();
  if (half == 0 && g < 2) {
    float m2 = mbuf[qsub][q], l2 = lbuf[qsub][q];
    float mn = fmaxf(m, m2);
    float c1 = __builtin_amdgcn_exp2f(m - mn);
    float c2 = __builtin_amdgcn_exp2f(m2 - mn);
    float inv = 1.f / (l * c1 + l2 * c2);
    int qrow = qt * 64 + qsub * 16 + q;
    float* ap = aws + ((size_t)b * 64 + n * 8) * HW_;
    #pragma unroll
    for (int r = 0; r < 4; ++r)
      ap[(size_t)(g * 4 + r) * HW_ + qrow] = (O[r] * c1 + obuf[qsub][q][g * 4 + r] * c2) * inv;
  }
}

// ---------------- K3: 1x1 conv on attention map (R6-proven) ----------------
// grid 256 = b(4) x ocq(16) x pt(4); 256 thr = 4 oc x 64 p-quads
__global__ __launch_bounds__(256) void k_attnconv(
    const float* __restrict__ aws, const float* __restrict__ w_attn, const float* __restrict__ b_attn,
    float* __restrict__ out)
{
  int bid = blockIdx.x;
  int pt  = bid & 3;
  int ocq = (bid >> 2) & 15;
  int b   = bid >> 6;
  int tid = threadIdx.x;
  int oc  = ocq * 4 + (tid >> 6);
  int p   = pt * 256 + (tid & 63) * 4;

  const float* wrow = w_attn + oc * 64;
  float bias = b_attn[oc];
  float4 acc = make_float4(bias, bias, bias, bias);
  const float* ab = aws + (size_t)b * 64 * HW_ + p;
  #pragma unroll 16
  for (int ci = 0; ci < 64; ++ci) {
    float wv = wrow[ci];
    float4 a4 = *(const float4*)(ab + (size_t)ci * HW_);
    acc.x = fmaf(wv, a4.x, acc.x);
    acc.y = fmaf(wv, a4.y, acc.y);
    acc.z = fmaf(wv, a4.z, acc.z);
    acc.w = fmaf(wv, a4.w, acc.w);
  }
  *(float4*)(out + ((size_t)b * 128 + 64 + oc) * HW_ + p) = acc;
}

extern "C" void kernel_launch(void* const* d_in, const int* in_sizes, int n_in,
                              void* d_out, int out_size, void* d_ws, size_t ws_size,
                              hipStream_t stream) {
  const float* x        = (const float*)d_in[0];
  const float* w_conv   = (const float*)d_in[1];
  const float* b_conv   = (const float*)d_in[2];
  const float* w_qkv    = (const float*)d_in[3];
  const float* b_qkv    = (const float*)d_in[4];
  const float* w_attn   = (const float*)d_in[5];
  const float* b_attn   = (const float*)d_in[6];
  const float* rel_h    = (const float*)d_in[7];
  const float* rel_w    = (const float*)d_in[8];
  float* out = (float*)d_out;

  float*  ws  = (float*)d_ws;
  float*  aws = ws;                               // [4][64][1024] f32 (1MB)
  ushort* qbf = (ushort*)(ws + 262144);           // [32][1024][8] bf16 (512KB)
  ushort* kbf = qbf + 262144;                     // [32][1024][8] bf16 (512KB)
  ushort* vtg = kbf + 262144;                     // [32][8][1024] bf16 (512KB)

  k_convs<<<512, 256, 0, stream>>>(x, w_conv, b_conv, w_qkv, b_qkv, out, qbf, kbf, vtg);
  k_attn<<<512, 512, 0, stream>>>(qbf, kbf, vtg, rel_h, rel_w, aws);
  k_attnconv<<<256, 256, 0, stream>>>(aws, w_attn, b_attn, out);
}

// Round 13
// 40.039 us; speedup vs baseline: 1.3847x; 1.1329x over previous
//
#include <hip/hip_runtime.h>
#include <math.h>

#define HW_ 1024

typedef __attribute__((ext_vector_type(4))) float   f32x4;
typedef __attribute__((ext_vector_type(8))) short   s16x8;

__device__ __forceinline__ unsigned bf16rne(float x) {
  unsigned u = __builtin_bit_cast(unsigned, x);
  u += 0x7FFF + ((u >> 16) & 1);
  return u >> 16;
}

__device__ __forceinline__ void store_oc(int oc, const float av[4],
    float* __restrict__ out, ushort* __restrict__ qbf, ushort* __restrict__ kbf,
    ushort* __restrict__ vtg, int b, int p)
{
  if (oc < 64) {
    float4 acc = make_float4(av[0], av[1], av[2], av[3]);
    *(float4*)(out + ((size_t)b * 128 + oc) * HW_ + p) = acc;
  } else if (oc < 128) {
    const float SC = 0.35355339059327373f * 1.4426950408889634f;  // dkh^-0.5 * log2e
    int qc = oc - 64, n = qc >> 3, d = qc & 7, bn = b * 8 + n;
    #pragma unroll
    for (int i = 0; i < 4; ++i)
      qbf[((size_t)bn * HW_ + p + i) * 8 + d] = (ushort)bf16rne(av[i] * SC);
  } else if (oc < 192) {
    int kc = oc - 128, n = kc >> 3, d = kc & 7, bn = b * 8 + n;
    #pragma unroll
    for (int i = 0; i < 4; ++i)
      kbf[((size_t)bn * HW_ + p + i) * 8 + d] = (ushort)bf16rne(av[i]);
  } else {
    int vc = oc - 192, n = vc >> 3, d = vc & 7, bn = b * 8 + n;
    #pragma unroll
    for (int i = 0; i < 4; ++i)
      vtg[((size_t)bn * 8 + d) * HW_ + p + i] = (ushort)bf16rne(av[i]);
  }
}

// ---------------- K1: fused 1x1 convs, 2 oc/thread (R11-proven) ----------------
// grid 512 = b(4) x ocp(32) x pt(4); 256 thr; thread: oc0=ocp*8+(tid>>6)*2, oc0+1
__global__ __launch_bounds__(256) void k_convs(
    const float* __restrict__ x, const float* __restrict__ w_conv, const float* __restrict__ b_conv,
    const float* __restrict__ w_qkv, const float* __restrict__ b_qkv,
    float* __restrict__ out,
    ushort* __restrict__ qbf, ushort* __restrict__ kbf, ushort* __restrict__ vtg)
{
  int bid = blockIdx.x;
  int pt  = bid & 3;
  int ocp = (bid >> 2) & 31;
  int b   = bid >> 7;
  int tid = threadIdx.x;
  int oc0 = ocp * 8 + (tid >> 6) * 2;      // even; pair stays within region
  int oc1 = oc0 + 1;
  int p   = pt * 256 + (tid & 63) * 4;

  const float* wrow0; const float* wrow1;
  float bias0, bias1;
  if (oc0 < 64) { wrow0 = w_conv + oc0 * 64; bias0 = b_conv[oc0];
                  wrow1 = w_conv + oc1 * 64; bias1 = b_conv[oc1]; }
  else          { wrow0 = w_qkv + (oc0 - 64) * 64; bias0 = b_qkv[oc0 - 64];
                  wrow1 = w_qkv + (oc1 - 64) * 64; bias1 = b_qkv[oc1 - 64]; }

  float4 a00 = make_float4(bias0, bias0, bias0, bias0);
  float4 a01 = make_float4(0.f, 0.f, 0.f, 0.f);
  float4 a10 = make_float4(bias1, bias1, bias1, bias1);
  float4 a11 = make_float4(0.f, 0.f, 0.f, 0.f);
  const float* xb = x + (size_t)b * 64 * HW_ + p;
  #pragma unroll 16
  for (int ci = 0; ci < 32; ++ci) {
    float4 x0 = *(const float4*)(xb + (size_t)ci * HW_);
    float4 x1 = *(const float4*)(xb + (size_t)(ci + 32) * HW_);
    float w00 = wrow0[ci], w01 = wrow0[ci + 32];
    float w10 = wrow1[ci], w11 = wrow1[ci + 32];
    a00.x = fmaf(w00, x0.x, a00.x); a01.x = fmaf(w01, x1.x, a01.x);
    a00.y = fmaf(w00, x0.y, a00.y); a01.y = fmaf(w01, x1.y, a01.y);
    a00.z = fmaf(w00, x0.z, a00.z); a01.z = fmaf(w01, x1.z, a01.z);
    a00.w = fmaf(w00, x0.w, a00.w); a01.w = fmaf(w01, x1.w, a01.w);
    a10.x = fmaf(w10, x0.x, a10.x); a11.x = fmaf(w11, x1.x, a11.x);
    a10.y = fmaf(w10, x0.y, a10.y); a11.y = fmaf(w11, x1.y, a11.y);
    a10.z = fmaf(w10, x0.z, a10.z); a11.z = fmaf(w11, x1.z, a11.z);
    a10.w = fmaf(w10, x0.w, a10.w); a11.w = fmaf(w11, x1.w, a11.w);
  }
  float av0[4] = {a00.x + a01.x, a00.y + a01.y, a00.z + a01.z, a00.w + a01.w};
  float av1[4] = {a10.x + a11.x, a10.y + a11.y, a10.z + a11.z, a10.w + a11.w};
  store_oc(oc0, av0, out, qbf, kbf, vtg, b, p);
  store_oc(oc1, av1, out, qbf, kbf, vtg, b, p);
}

// ---------------- K2: MFMA flash attention (R11 + K staged in LDS) ----------------
// grid 512 = bn(32) x qt(16); 512 thr = 8 waves: qsub(4) x key-half(2)
// wave: 16 q-cols x 512 keys. S^T = mfma(K_lds, Q^T, C=rel); P via per-wave
// swizzled LDS; O^T = mfma(V^T(+ones row), P^T, O); l rides in O row d=8.
__global__ __launch_bounds__(512, 4) void k_attn(
    const ushort* __restrict__ qbf, const ushort* __restrict__ kbf, const ushort* __restrict__ vtg,
    const float* __restrict__ rel_h, const float* __restrict__ rel_w,
    float* __restrict__ aws)
{
  __shared__ float rhd[64 * 33];
  __shared__ float rwd[64 * 33];
  __shared__ ushort P_lds[8][16][128];   // per-wave [q][key], 256B rows, XOR-swizzled
  __shared__ __align__(16) ushort K_lds[1024 * 8];  // whole head's K, [key][d], 16KB
  __shared__ float mbuf[4][16], lbuf[4][16];
  __shared__ float obuf[4][16][8];

  int bid = blockIdx.x;
  int qt = bid & 15;
  int bn = bid >> 4;
  int b = bn >> 3, n = bn & 7;
  int tid = threadIdx.x;
  int lane = tid & 63;
  int w = tid >> 6;
  int qsub = w & 3, half = w >> 2;

  // ---- stage K into LDS (coalesced, 2 keys x 16B per thread)
  {
    const uint4* src = (const uint4*)(kbf + (size_t)bn * HW_ * 8);
    uint4* dst = (uint4*)K_lds;
    dst[tid]       = src[tid];
    dst[tid + 512] = src[tid + 512];
  }

  // ---- build rel tables: rhd[qr][hp] = q.rel_h[hp-h+31], rwd[qr][wp] = q.rel_w[wp-w+31]
  {
    int qr = tid >> 3, qu = tid & 7;
    const ushort* qp = qbf + ((size_t)bn * HW_ + qt * 64 + qr) * 8;
    float qf[8];
    #pragma unroll
    for (int d = 0; d < 8; ++d) qf[d] = __builtin_bit_cast(float, (unsigned)qp[d] << 16);
    int h = (qt * 64 + qr) >> 5, ww = qr & 31;
    #pragma unroll
    for (int s = 0; s < 4; ++s) {
      int idx = qu * 4 + s;
      const float* rp = rel_h + (idx - h + 31) * 8;
      float a = 0.f;
      #pragma unroll
      for (int d = 0; d < 8; ++d) a = fmaf(qf[d], rp[d], a);
      rhd[qr * 33 + idx] = a;
      const float* rq = rel_w + (idx - ww + 31) * 8;
      float c = 0.f;
      #pragma unroll
      for (int d = 0; d < 8; ++d) c = fmaf(qf[d], rq[d], c);
      rwd[qr * 33 + idx] = c;
    }
  }
  __syncthreads();

  int q = lane & 15, g = lane >> 4;
  int qr = qsub * 16 + q;

  s16x8 qfrag = {0,0,0,0,0,0,0,0};
  if (lane < 16)
    qfrag = *(const s16x8*)(qbf + ((size_t)bn * HW_ + qt * 64 + qsub * 16 + lane) * 8);

  float rw2[2][4];
  #pragma unroll
  for (int r = 0; r < 4; ++r) {
    rw2[0][r] = rwd[qr * 33 + g * 4 + r];
    rw2[1][r] = rwd[qr * 33 + 16 + g * 4 + r];
  }

  const ushort* vbase = vtg + (size_t)bn * 8 * HW_;

  s16x8 vone;
  #pragma unroll
  for (int e = 0; e < 8; ++e) vone[e] = (short)0x3F80;   // bf16 1.0
  s16x8 vzero = {0,0,0,0,0,0,0,0};

  float m = -1e30f;
  f32x4 O = {0.f, 0.f, 0.f, 0.f};

  char* prow = (char*)&P_lds[w][0][0] + q * 256;
  int sw = (q & 7) << 4;

  #pragma unroll
  for (int bki = 0; bki < 4; ++bki) {
    int bk = half * 4 + bki;
    float rh4[4];
    #pragma unroll
    for (int j = 0; j < 4; ++j) rh4[j] = rhd[qr * 33 + bk * 4 + j];

    // ---- QK^T (S^T), rel logits as C-init; K from LDS (same index expr as R11)
    f32x4 s[8];
    __builtin_amdgcn_s_setprio(1);
    #pragma unroll
    for (int t = 0; t < 8; ++t) {
      f32x4 c;
      #pragma unroll
      for (int r = 0; r < 4; ++r) c[r] = rh4[t >> 1] + rw2[t & 1][r];
      s16x8 kf = {0,0,0,0,0,0,0,0};
      if (lane < 16)
        kf = *(const s16x8*)(K_lds + (size_t)(bk * 128 + t * 16 + lane) * 8);
      s[t] = __builtin_amdgcn_mfma_f32_16x16x32_bf16(kf, qfrag, c, 0, 0, 0);
    }
    __builtin_amdgcn_s_setprio(0);

    // ---- V fragments for this bk (issue loads before the pack/fence)
    s16x8 vfr[4];
    #pragma unroll
    for (int km = 0; km < 4; ++km) {
      if (q < 8)      vfr[km] = *(const s16x8*)(vbase + (size_t)q * HW_ + bk * 128 + km * 32 + g * 8);
      else if (q == 8) vfr[km] = vone;
      else             vfr[km] = vzero;
    }

    // ---- online softmax max (base-2 domain)
    float t8[8];
    #pragma unroll
    for (int t = 0; t < 8; ++t)
      t8[t] = fmaxf(fmaxf(s[t][0], s[t][1]), fmaxf(s[t][2], s[t][3]));
    float mx = fmaxf(fmaxf(fmaxf(t8[0], t8[1]), fmaxf(t8[2], t8[3])),
                     fmaxf(fmaxf(t8[4], t8[5]), fmaxf(t8[6], t8[7])));
    mx = fmaxf(mx, __shfl_xor(mx, 16));
    mx = fmaxf(mx, __shfl_xor(mx, 32));
    float mn = fmaxf(m, mx);
    float corr = __builtin_amdgcn_exp2f(m - mn);
    m = mn;

    #pragma unroll
    for (int t = 0; t < 8; ++t)
      #pragma unroll
      for (int r = 0; r < 4; ++r)
        s[t][r] = __builtin_amdgcn_exp2f(s[t][r] - mn);

    #pragma unroll
    for (int r = 0; r < 4; ++r) O[r] *= corr;

    // ---- pack P (RNE via cvt_pk) into swizzled per-wave LDS
    #pragma unroll
    for (int t = 0; t < 8; ++t) {
      unsigned w0, w1;
      asm("v_cvt_pk_bf16_f32 %0, %1, %2" : "=v"(w0) : "v"(s[t][0]), "v"(s[t][1]));
      asm("v_cvt_pk_bf16_f32 %0, %1, %2" : "=v"(w1) : "v"(s[t][2]), "v"(s[t][3]));
      *(uint2*)(prow + (((t * 32 + g * 8) ^ sw))) = make_uint2(w0, w1);
    }
    asm volatile("s_waitcnt lgkmcnt(0)" ::: "memory");

    // ---- PV: O^T += [V^T; ones] . P^T
    __builtin_amdgcn_s_setprio(1);
    #pragma unroll
    for (int km = 0; km < 4; ++km) {
      s16x8 pfrag = *(const s16x8*)(prow + ((km * 64 + g * 16) ^ sw));
      O = __builtin_amdgcn_mfma_f32_16x16x32_bf16(vfr[km], pfrag, O, 0, 0, 0);
    }
    __builtin_amdgcn_s_setprio(0);
  }

  // l = row d=8 of O^T (lane 32+q, reg 0)
  float l = __shfl(O[0], 32 + q);

  // ---- merge the two key-halves via LDS
  if (half == 1) {
    if (g < 2) {
      #pragma unroll
      for (int r = 0; r < 4; ++r) obuf[qsub][q][g * 4 + r] = O[r];
    }
    if (lane < 16) { mbuf[qsub][lane] = m; lbuf[qsub][lane] = l; }
  }
  __syncthreads();
  if (half == 0 && g < 2) {
    float m2 = mbuf[qsub][q], l2 = lbuf[qsub][q];
    float mn = fmaxf(m, m2);
    float c1 = __builtin_amdgcn_exp2f(m - mn);
    float c2 = __builtin_amdgcn_exp2f(m2 - mn);
    float inv = 1.f / (l * c1 + l2 * c2);
    int qrow = qt * 64 + qsub * 16 + q;
    float* ap = aws + ((size_t)b * 64 + n * 8) * HW_;
    #pragma unroll
    for (int r = 0; r < 4; ++r)
      ap[(size_t)(g * 4 + r) * HW_ + qrow] = (O[r] * c1 + obuf[qsub][q][g * 4 + r] * c2) * inv;
  }
}

// ---------------- K3: 1x1 conv on attention map (R6-proven) ----------------
// grid 256 = b(4) x ocq(16) x pt(4); 256 thr = 4 oc x 64 p-quads
__global__ __launch_bounds__(256) void k_attnconv(
    const float* __restrict__ aws, const float* __restrict__ w_attn, const float* __restrict__ b_attn,
    float* __restrict__ out)
{
  int bid = blockIdx.x;
  int pt  = bid & 3;
  int ocq = (bid >> 2) & 15;
  int b   = bid >> 6;
  int tid = threadIdx.x;
  int oc  = ocq * 4 + (tid >> 6);
  int p   = pt * 256 + (tid & 63) * 4;

  const float* wrow = w_attn + oc * 64;
  float bias = b_attn[oc];
  float4 acc = make_float4(bias, bias, bias, bias);
  const float* ab = aws + (size_t)b * 64 * HW_ + p;
  #pragma unroll 16
  for (int ci = 0; ci < 64; ++ci) {
    float wv = wrow[ci];
    float4 a4 = *(const float4*)(ab + (size_t)ci * HW_);
    acc.x = fmaf(wv, a4.x, acc.x);
    acc.y = fmaf(wv, a4.y, acc.y);
    acc.z = fmaf(wv, a4.z, acc.z);
    acc.w = fmaf(wv, a4.w, acc.w);
  }
  *(float4*)(out + ((size_t)b * 128 + 64 + oc) * HW_ + p) = acc;
}

extern "C" void kernel_launch(void* const* d_in, const int* in_sizes, int n_in,
                              void* d_out, int out_size, void* d_ws, size_t ws_size,
                              hipStream_t stream) {
  const float* x        = (const float*)d_in[0];
  const float* w_conv   = (const float*)d_in[1];
  const float* b_conv   = (const float*)d_in[2];
  const float* w_qkv    = (const float*)d_in[3];
  const float* b_qkv    = (const float*)d_in[4];
  const float* w_attn   = (const float*)d_in[5];
  const float* b_attn   = (const float*)d_in[6];
  const float* rel_h    = (const float*)d_in[7];
  const float* rel_w    = (const float*)d_in[8];
  float* out = (float*)d_out;

  float*  ws  = (float*)d_ws;
  float*  aws = ws;                               // [4][64][1024] f32 (1MB)
  ushort* qbf = (ushort*)(ws + 262144);           // [32][1024][8] bf16 (512KB)
  ushort* kbf = qbf + 262144;                     // [32][1024][8] bf16 (512KB)
  ushort* vtg = kbf + 262144;                     // [32][8][1024] bf16 (512KB)

  k_convs<<<512, 256, 0, stream>>>(x, w_conv, b_conv, w_qkv, b_qkv, out, qbf, kbf, vtg);
  k_attn<<<512, 512, 0, stream>>>(qbf, kbf, vtg, rel_h, rel_w, aws);
  k_attnconv<<<256, 256, 0, stream>>>(aws, w_attn, b_attn, out);
}

// Round 14
// 38.224 us; speedup vs baseline: 1.4505x; 1.0475x over previous
//
#include <hip/hip_runtime.h>
#include <math.h>

#define HW_ 1024

typedef __attribute__((ext_vector_type(4))) float   f32x4;
typedef __attribute__((ext_vector_type(8))) short   s16x8;

__device__ __forceinline__ unsigned bf16rne(float x) {
  unsigned u = __builtin_bit_cast(unsigned, x);
  u += 0x7FFF + ((u >> 16) & 1);
  return u >> 16;
}
__device__ __forceinline__ float bf2f(ushort u) {
  return __builtin_bit_cast(float, (unsigned)u << 16);
}

__device__ __forceinline__ void store_oc(int oc, const float av[4],
    float* __restrict__ out, ushort* __restrict__ qbf, ushort* __restrict__ kbf,
    ushort* __restrict__ vtg, int b, int p)
{
  if (oc < 64) {
    float4 acc = make_float4(av[0], av[1], av[2], av[3]);
    *(float4*)(out + ((size_t)b * 128 + oc) * HW_ + p) = acc;
  } else if (oc < 128) {
    const float SC = 0.35355339059327373f * 1.4426950408889634f;  // dkh^-0.5 * log2e
    int qc = oc - 64, n = qc >> 3, d = qc & 7, bn = b * 8 + n;
    #pragma unroll
    for (int i = 0; i < 4; ++i)
      qbf[((size_t)bn * HW_ + p + i) * 8 + d] = (ushort)bf16rne(av[i] * SC);
  } else if (oc < 192) {
    int kc = oc - 128, n = kc >> 3, d = kc & 7, bn = b * 8 + n;
    #pragma unroll
    for (int i = 0; i < 4; ++i)
      kbf[((size_t)bn * HW_ + p + i) * 8 + d] = (ushort)bf16rne(av[i]);
  } else {
    int vc = oc - 192, n = vc >> 3, d = vc & 7, bn = b * 8 + n;
    #pragma unroll
    for (int i = 0; i < 4; ++i)
      vtg[((size_t)bn * 8 + d) * HW_ + p + i] = (ushort)bf16rne(av[i]);
  }
}

// ---------------- K1: fused 1x1 convs, 2 oc/thread (R11-proven) ----------------
// grid 512 = b(4) x ocp(32) x pt(4); 256 thr; thread: oc0=ocp*8+(tid>>6)*2, oc0+1
__global__ __launch_bounds__(256) void k_convs(
    const float* __restrict__ x, const float* __restrict__ w_conv, const float* __restrict__ b_conv,
    const float* __restrict__ w_qkv, const float* __restrict__ b_qkv,
    float* __restrict__ out,
    ushort* __restrict__ qbf, ushort* __restrict__ kbf, ushort* __restrict__ vtg)
{
  int bid = blockIdx.x;
  int pt  = bid & 3;
  int ocp = (bid >> 2) & 31;
  int b   = bid >> 7;
  int tid = threadIdx.x;
  int oc0 = ocp * 8 + (tid >> 6) * 2;      // even; pair stays within region
  int oc1 = oc0 + 1;
  int p   = pt * 256 + (tid & 63) * 4;

  const float* wrow0; const float* wrow1;
  float bias0, bias1;
  if (oc0 < 64) { wrow0 = w_conv + oc0 * 64; bias0 = b_conv[oc0];
                  wrow1 = w_conv + oc1 * 64; bias1 = b_conv[oc1]; }
  else          { wrow0 = w_qkv + (oc0 - 64) * 64; bias0 = b_qkv[oc0 - 64];
                  wrow1 = w_qkv + (oc1 - 64) * 64; bias1 = b_qkv[oc1 - 64]; }

  float4 a00 = make_float4(bias0, bias0, bias0, bias0);
  float4 a01 = make_float4(0.f, 0.f, 0.f, 0.f);
  float4 a10 = make_float4(bias1, bias1, bias1, bias1);
  float4 a11 = make_float4(0.f, 0.f, 0.f, 0.f);
  const float* xb = x + (size_t)b * 64 * HW_ + p;
  #pragma unroll 16
  for (int ci = 0; ci < 32; ++ci) {
    float4 x0 = *(const float4*)(xb + (size_t)ci * HW_);
    float4 x1 = *(const float4*)(xb + (size_t)(ci + 32) * HW_);
    float w00 = wrow0[ci], w01 = wrow0[ci + 32];
    float w10 = wrow1[ci], w11 = wrow1[ci + 32];
    a00.x = fmaf(w00, x0.x, a00.x); a01.x = fmaf(w01, x1.x, a01.x);
    a00.y = fmaf(w00, x0.y, a00.y); a01.y = fmaf(w01, x1.y, a01.y);
    a00.z = fmaf(w00, x0.z, a00.z); a01.z = fmaf(w01, x1.z, a01.z);
    a00.w = fmaf(w00, x0.w, a00.w); a01.w = fmaf(w01, x1.w, a01.w);
    a10.x = fmaf(w10, x0.x, a10.x); a11.x = fmaf(w11, x1.x, a11.x);
    a10.y = fmaf(w10, x0.y, a10.y); a11.y = fmaf(w11, x1.y, a11.y);
    a10.z = fmaf(w10, x0.z, a10.z); a11.z = fmaf(w11, x1.z, a11.z);
    a10.w = fmaf(w10, x0.w, a10.w); a11.w = fmaf(w11, x1.w, a11.w);
  }
  float av0[4] = {a00.x + a01.x, a00.y + a01.y, a00.z + a01.z, a00.w + a01.w};
  float av1[4] = {a10.x + a11.x, a10.y + a11.y, a10.z + a11.z, a10.w + a11.w};
  store_oc(oc0, av0, out, qbf, kbf, vtg, b, p);
  store_oc(oc1, av1, out, qbf, kbf, vtg, b, p);
}

// ---------------- K2: MFMA flash attention (R13 + V staged in LDS, bf16 rel tables) ----------------
// grid 512 = bn(32) x qt(16); 512 thr = 8 waves: qsub(4) x key-half(2)
// wave: 16 q-cols x 512 keys. S^T = mfma(K_lds, Q^T, C=rel); P via per-wave
// swizzled LDS; O^T = mfma(V_lds^T(+ones row), P^T, O); l rides in O row d=8.
__global__ __launch_bounds__(512, 4) void k_attn(
    const ushort* __restrict__ qbf, const ushort* __restrict__ kbf, const ushort* __restrict__ vtg,
    const float* __restrict__ rel_h, const float* __restrict__ rel_w,
    float* __restrict__ aws)
{
  __shared__ ushort rhd[64 * 36];        // bf16, stride 36 (8B-aligned rows of 4)
  __shared__ ushort rwd[64 * 36];
  __shared__ ushort P_lds[8][16][128];   // per-wave [q][key], 256B rows, XOR-swizzled
  __shared__ __align__(16) ushort K_lds[1024 * 8];  // whole head's K, [key][d], 16KB
  __shared__ __align__(16) ushort V_lds[1024 * 8];  // whole head's V^T, [d][key], swizzled, 16KB
  __shared__ float mbuf[4][16], lbuf[4][16];
  __shared__ float obuf[4][16][8];

  int bid = blockIdx.x;
  int qt = bid & 15;
  int bn = bid >> 4;
  int b = bn >> 3, n = bn & 7;
  int tid = threadIdx.x;
  int lane = tid & 63;
  int w = tid >> 6;
  int qsub = w & 3, half = w >> 2;

  // ---- stage K and V into LDS (coalesced global reads; V LDS-dst swizzled: unit ^= d&7)
  {
    const uint4* ksrc = (const uint4*)(kbf + (size_t)bn * HW_ * 8);
    const uint4* vsrc = (const uint4*)(vtg + (size_t)bn * 8 * HW_);
    uint4* kdst = (uint4*)K_lds;
    uint4* vdst = (uint4*)V_lds;
    kdst[tid]       = ksrc[tid];
    kdst[tid + 512] = ksrc[tid + 512];
    int g0 = tid, g1 = tid + 512;
    vdst[(g0 & ~127) | ((g0 & 127) ^ ((g0 >> 7) & 7))] = vsrc[g0];
    vdst[(g1 & ~127) | ((g1 & 127) ^ ((g1 >> 7) & 7))] = vsrc[g1];
  }

  // ---- build rel tables (bf16): rhd[qr][hp] = q.rel_h[hp-h+31], rwd[qr][wp] = q.rel_w[wp-w+31]
  {
    int qr = tid >> 3, qu = tid & 7;
    const ushort* qp = qbf + ((size_t)bn * HW_ + qt * 64 + qr) * 8;
    float qf[8];
    #pragma unroll
    for (int d = 0; d < 8; ++d) qf[d] = bf2f(qp[d]);
    int h = (qt * 64 + qr) >> 5, ww = qr & 31;
    #pragma unroll
    for (int s = 0; s < 4; ++s) {
      int idx = qu * 4 + s;
      const float* rp = rel_h + (idx - h + 31) * 8;
      float a = 0.f;
      #pragma unroll
      for (int d = 0; d < 8; ++d) a = fmaf(qf[d], rp[d], a);
      rhd[qr * 36 + idx] = (ushort)bf16rne(a);
      const float* rq = rel_w + (idx - ww + 31) * 8;
      float c = 0.f;
      #pragma unroll
      for (int d = 0; d < 8; ++d) c = fmaf(qf[d], rq[d], c);
      rwd[qr * 36 + idx] = (ushort)bf16rne(c);
    }
  }
  __syncthreads();

  int q = lane & 15, g = lane >> 4;
  int qr = qsub * 16 + q;

  s16x8 qfrag = {0,0,0,0,0,0,0,0};
  if (lane < 16)
    qfrag = *(const s16x8*)(qbf + ((size_t)bn * HW_ + qt * 64 + qsub * 16 + lane) * 8);

  float rw2[2][4];
  #pragma unroll
  for (int r = 0; r < 4; ++r) {
    rw2[0][r] = bf2f(rwd[qr * 36 + g * 4 + r]);
    rw2[1][r] = bf2f(rwd[qr * 36 + 16 + g * 4 + r]);
  }

  s16x8 vone;
  #pragma unroll
  for (int e = 0; e < 8; ++e) vone[e] = (short)0x3F80;   // bf16 1.0
  s16x8 vzero = {0,0,0,0,0,0,0,0};

  float m = -1e30f;
  f32x4 O = {0.f, 0.f, 0.f, 0.f};

  char* prow = (char*)&P_lds[w][0][0] + q * 256;
  int sw = (q & 7) << 4;

  #pragma unroll
  for (int bki = 0; bki < 4; ++bki) {
    int bk = half * 4 + bki;
    float rh4[4];
    #pragma unroll
    for (int j = 0; j < 4; ++j) rh4[j] = bf2f(rhd[qr * 36 + bk * 4 + j]);

    // ---- QK^T (S^T), rel logits as C-init; K from LDS
    f32x4 s[8];
    __builtin_amdgcn_s_setprio(1);
    #pragma unroll
    for (int t = 0; t < 8; ++t) {
      f32x4 c;
      #pragma unroll
      for (int r = 0; r < 4; ++r) c[r] = rh4[t >> 1] + rw2[t & 1][r];
      s16x8 kf = {0,0,0,0,0,0,0,0};
      if (lane < 16)
        kf = *(const s16x8*)(K_lds + (size_t)(bk * 128 + t * 16 + lane) * 8);
      s[t] = __builtin_amdgcn_mfma_f32_16x16x32_bf16(kf, qfrag, c, 0, 0, 0);
    }
    __builtin_amdgcn_s_setprio(0);

    // ---- V fragments from swizzled LDS
    s16x8 vfr[4];
    #pragma unroll
    for (int km = 0; km < 4; ++km) {
      if (q < 8)
        vfr[km] = *(const s16x8*)((const char*)V_lds + q * 2048 +
                                  (((bk * 16 + km * 4 + g) ^ q) << 4));
      else if (q == 8) vfr[km] = vone;
      else             vfr[km] = vzero;
    }

    // ---- online softmax max (base-2 domain)
    float t8[8];
    #pragma unroll
    for (int t = 0; t < 8; ++t)
      t8[t] = fmaxf(fmaxf(s[t][0], s[t][1]), fmaxf(s[t][2], s[t][3]));
    float mx = fmaxf(fmaxf(fmaxf(t8[0], t8[1]), fmaxf(t8[2], t8[3])),
                     fmaxf(fmaxf(t8[4], t8[5]), fmaxf(t8[6], t8[7])));
    mx = fmaxf(mx, __shfl_xor(mx, 16));
    mx = fmaxf(mx, __shfl_xor(mx, 32));
    float mn = fmaxf(m, mx);
    float corr = __builtin_amdgcn_exp2f(m - mn);
    m = mn;

    #pragma unroll
    for (int t = 0; t < 8; ++t)
      #pragma unroll
      for (int r = 0; r < 4; ++r)
        s[t][r] = __builtin_amdgcn_exp2f(s[t][r] - mn);

    #pragma unroll
    for (int r = 0; r < 4; ++r) O[r] *= corr;

    // ---- pack P (RNE via cvt_pk) into swizzled per-wave LDS
    #pragma unroll
    for (int t = 0; t < 8; ++t) {
      unsigned w0, w1;
      asm("v_cvt_pk_bf16_f32 %0, %1, %2" : "=v"(w0) : "v"(s[t][0]), "v"(s[t][1]));
      asm("v_cvt_pk_bf16_f32 %0, %1, %2" : "=v"(w1) : "v"(s[t][2]), "v"(s[t][3]));
      *(uint2*)(prow + (((t * 32 + g * 8) ^ sw))) = make_uint2(w0, w1);
    }
    asm volatile("s_waitcnt lgkmcnt(0)" ::: "memory");

    // ---- PV: O^T += [V^T; ones] . P^T
    __builtin_amdgcn_s_setprio(1);
    #pragma unroll
    for (int km = 0; km < 4; ++km) {
      s16x8 pfrag = *(const s16x8*)(prow + ((km * 64 + g * 16) ^ sw));
      O = __builtin_amdgcn_mfma_f32_16x16x32_bf16(vfr[km], pfrag, O, 0, 0, 0);
    }
    __builtin_amdgcn_s_setprio(0);
  }

  // l = row d=8 of O^T (lane 32+q, reg 0)
  float l = __shfl(O[0], 32 + q);

  // ---- merge the two key-halves via LDS
  if (half == 1) {
    if (g < 2) {
      #pragma unroll
      for (int r = 0; r < 4; ++r) obuf[qsub][q][g * 4 + r] = O[r];
    }
    if (lane < 16) { mbuf[qsub][lane] = m; lbuf[qsub][lane] = l; }
  }
  __syncthreads();
  if (half == 0 && g < 2) {
    float m2 = mbuf[qsub][q], l2 = lbuf[qsub][q];
    float mn = fmaxf(m, m2);
    float c1 = __builtin_amdgcn_exp2f(m - mn);
    float c2 = __builtin_amdgcn_exp2f(m2 - mn);
    float inv = 1.f / (l * c1 + l2 * c2);
    int qrow = qt * 64 + qsub * 16 + q;
    float* ap = aws + ((size_t)b * 64 + n * 8) * HW_;
    #pragma unroll
    for (int r = 0; r < 4; ++r)
      ap[(size_t)(g * 4 + r) * HW_ + qrow] = (O[r] * c1 + obuf[qsub][q][g * 4 + r] * c2) * inv;
  }
}

// ---------------- K3: 1x1 conv on attention map, ci halved across half-waves ----------------
// grid 512 = b(4) x ocq(16) x pt(8); 256 thr = 4 oc x [2 ci-halves x 32 p-quads]
__global__ __launch_bounds__(256) void k_attnconv(
    const float* __restrict__ aws, const float* __restrict__ w_attn, const float* __restrict__ b_attn,
    float* __restrict__ out)
{
  int bid = blockIdx.x;
  int pt  = bid & 7;
  int ocq = (bid >> 3) & 15;
  int b   = bid >> 7;
  int tid = threadIdx.x;
  int lane = tid & 63;
  int oc  = ocq * 4 + (tid >> 6);
  int hf  = lane >> 5;                 // ci half: 0 -> ci 0..31, 1 -> ci 32..63
  int p   = pt * 128 + (lane & 31) * 4;
  int ci0 = hf * 32;

  const float* wrow = w_attn + oc * 64 + ci0;
  const float* ab = aws + (size_t)b * 64 * HW_ + (size_t)ci0 * HW_ + p;
  float4 acc = make_float4(0.f, 0.f, 0.f, 0.f);
  #pragma unroll 16
  for (int ci = 0; ci < 32; ++ci) {
    float wv = wrow[ci];
    float4 a4 = *(const float4*)(ab + (size_t)ci * HW_);
    acc.x = fmaf(wv, a4.x, acc.x);
    acc.y = fmaf(wv, a4.y, acc.y);
    acc.z = fmaf(wv, a4.z, acc.z);
    acc.w = fmaf(wv, a4.w, acc.w);
  }
  acc.x += __shfl_xor(acc.x, 32);
  acc.y += __shfl_xor(acc.y, 32);
  acc.z += __shfl_xor(acc.z, 32);
  acc.w += __shfl_xor(acc.w, 32);
  if (hf == 0) {
    float bias = b_attn[oc];
    float4 r = make_float4(acc.x + bias, acc.y + bias, acc.z + bias, acc.w + bias);
    *(float4*)(out + ((size_t)b * 128 + 64 + oc) * HW_ + p) = r;
  }
}

extern "C" void kernel_launch(void* const* d_in, const int* in_sizes, int n_in,
                              void* d_out, int out_size, void* d_ws, size_t ws_size,
                              hipStream_t stream) {
  const float* x        = (const float*)d_in[0];
  const float* w_conv   = (const float*)d_in[1];
  const float* b_conv   = (const float*)d_in[2];
  const float* w_qkv    = (const float*)d_in[3];
  const float* b_qkv    = (const float*)d_in[4];
  const float* w_attn   = (const float*)d_in[5];
  const float* b_attn   = (const float*)d_in[6];
  const float* rel_h    = (const float*)d_in[7];
  const float* rel_w    = (const float*)d_in[8];
  float* out = (float*)d_out;

  float*  ws  = (float*)d_ws;
  float*  aws = ws;                               // [4][64][1024] f32 (1MB)
  ushort* qbf = (ushort*)(ws + 262144);           // [32][1024][8] bf16 (512KB)
  ushort* kbf = qbf + 262144;                     // [32][1024][8] bf16 (512KB)
  ushort* vtg = kbf + 262144;                     // [32][8][1024] bf16 (512KB)

  k_convs<<<512, 256, 0, stream>>>(x, w_conv, b_conv, w_qkv, b_qkv, out, qbf, kbf, vtg);
  k_attn<<<512, 512, 0, stream>>>(qbf, kbf, vtg, rel_h, rel_w, aws);
  k_attnconv<<<512, 256, 0, stream>>>(aws, w_attn, b_attn, out);
}